// Round 12
// baseline (147.701 us; speedup 1.0000x reference)
//
#include <hip/hip_runtime.h>

// Fused capsule conv + dynamic routing: 2 pixels/block, MFMA, XCD-ownership.
// x:      [8, 32, 8, 32, 32] f32   (bs, ci, ni, hi, wi)
// conv_w: [256, 8, 3, 3]     f32   (co*no, ni, kh, kw)
// bias:   [32, 8, 1, 1]      f32
// out:    [8, 32, 8, 32, 32] f32   (bs, co, no, ho, wo)
//
// R10 (86.7us) + micro-op pass at CONSTANT register pressure (64 VGPR +
// 64 AGPR = exactly the LB(256,4) 128-reg cap; any growth drops a block):
//  - squash & softmax-inv via native v_sqrt_f32 / v_rcp_f32 (1-inst TRANS,
//    replaces div/sqrt expansions; +1e-7 rel error, invisible)
//  - A-staging bf16 convert via v_cvt_pk_bf16_f32 (9 insts vs 18 manual
//    RNE twiddles; identical RNE rounding)
//  - logits px-packed [ci][co][2]: softmax 4xb64 reads (was 8xb32),
//    dist 2xb64 writes (+2 b64 reads at it1) (was 8 scalar / 8 RMW)
// Kept: pixel-pair ILP-2, single-term bf16 GEMM (K=96), 5 barriers,
// XCD-ownership swizzle, butterfly dist reduce, float2 stores.

typedef __attribute__((ext_vector_type(8))) short short8;
typedef __attribute__((ext_vector_type(4))) float f32x4;

#define LSTR 104   // A row stride in ushorts (208 B)
#define KP   96    // packed K per col: [hi 72][zero 24]
#define RSTR 36    // routeT row stride (f32)
#define LGS  66    // packed logits row stride in f32 ([co 32][2] + pad pair)

__device__ __forceinline__ ushort f2bf_rne(float f) {
    unsigned u = __float_as_uint(f);
    return (ushort)((u + 0x7fffu + ((u >> 16) & 1u)) >> 16);
}
__device__ __forceinline__ float fast_rcp(float x) {
    float r; asm("v_rcp_f32 %0, %1" : "=v"(r) : "v"(x)); return r;
}
__device__ __forceinline__ float fast_sqrt(float x) {
    float r; asm("v_sqrt_f32 %0, %1" : "=v"(r) : "v"(x)); return r;
}
__device__ __forceinline__ unsigned cvt_pk_bf16(float lo, float hi) {
    unsigned r;
    asm("v_cvt_pk_bf16_f32 %0, %1, %2" : "=v"(r) : "v"(lo), "v"(hi));
    return r;
}

__global__ void prep_w(const float* __restrict__ cw, ushort* __restrict__ wp) {
    int e = blockIdx.x * 256 + threadIdx.x;   // [col=256][k=96]
    int col = e / KP, k = e - col * KP;
    float v = (k < 72) ? cw[col * 72 + k] : 0.0f;
    wp[e] = f2bf_rne(v);
}

__global__ __launch_bounds__(256, 4)
void caps_mfma2(const float* __restrict__ x,
                const ushort* __restrict__ wp,
                const float* __restrict__ bias,
                float* __restrict__ out)
{
    __shared__ ushort A[64 * LSTR];         // 13,312 B
    __shared__ float  lgp[32 * LGS];        //  8,448 B  [ci][co][2px]
    __shared__ float  routeT[2][32 * RSTR]; //  9,216 B  [px][co][ci]

    const int t    = threadIdx.x;
    const int braw = blockIdx.x;                 // grid = 4096
    // XCD-ownership swizzle (bijective, 4096 = 8*512): XCD k owns batch k.
    const int bid = ((braw & 7) << 9) | (braw >> 3);
    const int b   = bid >> 9;
    const int q   = bid & 511;
    const int hw0 = q << 1;                      // even; pair = (hw0, hw0+1)
    const int h   = hw0 >> 5;
    const int w0  = hw0 & 31;                    // even, <= 30

    // ---- stage A rows: thread t <-> (row = t>>2 = px*32+ci, ni in {2qn,2qn+1})
    {
        const int row = t >> 2, qn = t & 3;
        const int px = row >> 5, ci = row & 31;
        const int wpx = w0 + px;
        const float* xb0 = x + (((size_t)((b * 32 + ci) * 8 + qn * 2)) << 10);
        const float* xb1 = xb0 + 1024;
        float farr[18];
        #pragma unroll
        for (int kh = 0; kh < 3; ++kh) {
            int hy = h + kh - 1;
            bool vh = (unsigned)hy < 32u;
            int base = hy << 5;
            #pragma unroll
            for (int c = 0; c < 3; ++c) {
                int wx = wpx + c - 1;
                bool ok = vh && ((unsigned)wx < 32u);
                farr[kh * 3 + c]     = ok ? xb0[base + wx] : 0.0f;
                farr[9 + kh * 3 + c] = ok ? xb1[base + wx] : 0.0f;
            }
        }
        // packed uint writes: shorts [row*LSTR + qn*18, +18)
        uint* Au = reinterpret_cast<uint*>(A);
        int hbase = row * (LSTR / 2) + qn * 9;
        #pragma unroll
        for (int i = 0; i < 9; ++i)
            Au[hbase + i] = cvt_pk_bf16(farr[2 * i], farr[2 * i + 1]);
        // zero K-pad shorts 72..103 (16 uints/row, 4 threads -> 4 each)
        int pbase = row * (LSTR / 2) + 36 + qn * 4;
        Au[pbase + 0] = 0u; Au[pbase + 1] = 0u;
        Au[pbase + 2] = 0u; Au[pbase + 3] = 0u;
    }
    __syncthreads();                     // barrier 1 (staging -> GEMM)

    const int lane = t & 63, wv = t >> 6;
    const int lc = lane & 15, grp = lane >> 4;
    const int no = lane & 7;
    const int par = (lane >> 3) & 1;

    // ---- GEMM: D[64 rows][256 cols], rows = px*32+ci. 3 k-steps of 32.
    f32x4 acc[4][4];
    #pragma unroll
    for (int mt = 0; mt < 4; ++mt)
        #pragma unroll
        for (int j = 0; j < 4; ++j) acc[mt][j] = (f32x4){0.f, 0.f, 0.f, 0.f};

    #pragma unroll
    for (int ks = 0; ks < 3; ++ks) {
        short8 bq[4];
        #pragma unroll
        for (int j = 0; j < 4; ++j) {
            int col = wv * 64 + j * 16 + lc;
            bq[j] = *reinterpret_cast<const short8*>(wp + col * KP + ks * 32 + grp * 8);
        }
        #pragma unroll
        for (int mt = 0; mt < 4; ++mt) {
            short8 af = *reinterpret_cast<const short8*>(A + (mt * 16 + lc) * LSTR + ks * 32 + grp * 8);
            #pragma unroll
            for (int j = 0; j < 4; ++j)
                acc[mt][j] = __builtin_amdgcn_mfma_f32_16x16x32_bf16(af, bq[j], acc[mt][j], 0, 0, 0);
        }
    }
    // no barrier: A is read-only from here; routing uses separate buffers

    float bj[4];
    #pragma unroll
    for (int j = 0; j < 4; ++j) bj[j] = bias[wv * 64 + j * 16 + lc];

    const int ci_s = t >> 3, j_s = t & 7;
    const int ci_w = ((no >> 2) << 4) + (grp << 2) + (no & 3);   // dist write row
    float act_[2][4];

    // ================= iteration 0: route = 1/32 exactly =================
    #pragma unroll
    for (int px = 0; px < 2; ++px) {
        #pragma unroll
        for (int j = 0; j < 4; ++j) {
            const f32x4 a0 = acc[px * 2][j], a1 = acc[px * 2 + 1][j];
            float p = a0[0] + a0[1] + a0[2] + a0[3] + a1[0] + a1[1] + a1[2] + a1[3];
            p += __shfl_xor(p, 16);
            p += __shfl_xor(p, 32);             // sum over 32 ci
            p = p * 0.03125f + bj[j];
            float s2 = p * p;
            s2 += __shfl_xor(s2, 1);
            s2 += __shfl_xor(s2, 2);
            s2 += __shfl_xor(s2, 4);            // sum over no
            act_[px][j] = p * fast_sqrt(s2) * fast_rcp(1.0f + s2);
        }
    }
    // distances -> logits (pure b64 write of all (ci,co) pairs, both px)
    #pragma unroll
    for (int j = 0; j < 4; ++j) {
        const int co = (wv << 3) + 2 * j + par;
        float rpx[2];
        #pragma unroll
        for (int px = 0; px < 2; ++px) {
            float a = act_[px][j];
            float d[8];
            #pragma unroll
            for (int r = 0; r < 4; ++r) { d[r] = acc[px * 2][j][r] * a; d[4 + r] = acc[px * 2 + 1][j][r] * a; }
            const bool b4 = (no & 4) != 0, b2 = (no & 2) != 0, b1 = (no & 1) != 0;
            float e[4];
            #pragma unroll
            for (int k = 0; k < 4; ++k) {
                float keep = b4 ? d[k + 4] : d[k];
                float send = b4 ? d[k] : d[k + 4];
                e[k] = keep + __shfl_xor(send, 4);
            }
            float f2_[2];
            #pragma unroll
            for (int k = 0; k < 2; ++k) {
                float keep = b2 ? e[k + 2] : e[k];
                float send = b2 ? e[k] : e[k + 2];
                f2_[k] = keep + __shfl_xor(send, 2);
            }
            float keep = b1 ? f2_[1] : f2_[0];
            float send = b1 ? f2_[0] : f2_[1];
            rpx[px] = keep + __shfl_xor(send, 1);
        }
        float2 v; v.x = rpx[0]; v.y = rpx[1];
        *(reinterpret_cast<float2*>(lgp + ci_w * LGS) + co) = v;
    }
    __syncthreads();                     // barrier 2 (dist0 -> softmax1)

    // ================= iterations 1 and 2 =================
    for (int it = 1; it <= 2; ++it) {
        // (a) softmax over co, both px from packed b64 reads (no max-sub:
        //     |logits| small); store transposed routeT[px][co][ci]
        {
            const float2* lrow = reinterpret_cast<const float2*>(lgp + ci_s * LGS);
            float2 L0 = lrow[j_s], L1 = lrow[j_s + 8];
            float2 L2 = lrow[j_s + 16], L3 = lrow[j_s + 24];
            // px0
            {
                float e0 = __expf(L0.x), e1 = __expf(L1.x);
                float e2 = __expf(L2.x), e3 = __expf(L3.x);
                float s = e0 + e1 + e2 + e3;
                s += __shfl_xor(s, 1); s += __shfl_xor(s, 2); s += __shfl_xor(s, 4);
                float inv = fast_rcp(s);
                float* rt = routeT[0];
                rt[(j_s)      * RSTR + ci_s] = e0 * inv;
                rt[(j_s + 8)  * RSTR + ci_s] = e1 * inv;
                rt[(j_s + 16) * RSTR + ci_s] = e2 * inv;
                rt[(j_s + 24) * RSTR + ci_s] = e3 * inv;
            }
            // px1
            {
                float e0 = __expf(L0.y), e1 = __expf(L1.y);
                float e2 = __expf(L2.y), e3 = __expf(L3.y);
                float s = e0 + e1 + e2 + e3;
                s += __shfl_xor(s, 1); s += __shfl_xor(s, 2); s += __shfl_xor(s, 4);
                float inv = fast_rcp(s);
                float* rt = routeT[1];
                rt[(j_s)      * RSTR + ci_s] = e0 * inv;
                rt[(j_s + 8)  * RSTR + ci_s] = e1 * inv;
                rt[(j_s + 16) * RSTR + ci_s] = e2 * inv;
                rt[(j_s + 24) * RSTR + ci_s] = e3 * inv;
            }
        }
        __syncthreads();                 // barrier 3 / 5 (routeT -> preact)

        // (b) preactivate (ci-reduce xor16/32) + squash (no-reduce xor1/2/4)
        #pragma unroll
        for (int px = 0; px < 2; ++px) {
            const float* rt = routeT[px];
            #pragma unroll
            for (int j = 0; j < 4; ++j) {
                int co = (wv << 3) + 2 * j + par;
                f32x4 r0 = *reinterpret_cast<const f32x4*>(rt + co * RSTR + grp * 4);
                f32x4 r1 = *reinterpret_cast<const f32x4*>(rt + co * RSTR + 16 + grp * 4);
                float p = 0.0f;
                #pragma unroll
                for (int r = 0; r < 4; ++r) p = fmaf(r0[r], acc[px * 2][j][r], p);
                #pragma unroll
                for (int r = 0; r < 4; ++r) p = fmaf(r1[r], acc[px * 2 + 1][j][r], p);
                p += __shfl_xor(p, 16);
                p += __shfl_xor(p, 32);
                p += bj[j];
                float s2 = p * p;
                s2 += __shfl_xor(s2, 1);
                s2 += __shfl_xor(s2, 2);
                s2 += __shfl_xor(s2, 4);
                act_[px][j] = p * fast_sqrt(s2) * fast_rcp(1.0f + s2);
            }
        }
        if (it == 2) break;

        // (c) distances += : packed b64 read-add-write, both px
        #pragma unroll
        for (int j = 0; j < 4; ++j) {
            const int co = (wv << 3) + 2 * j + par;
            float rpx[2];
            #pragma unroll
            for (int px = 0; px < 2; ++px) {
                float a = act_[px][j];
                float d[8];
                #pragma unroll
                for (int r = 0; r < 4; ++r) { d[r] = acc[px * 2][j][r] * a; d[4 + r] = acc[px * 2 + 1][j][r] * a; }
                const bool b4 = (no & 4) != 0, b2 = (no & 2) != 0, b1 = (no & 1) != 0;
                float e[4];
                #pragma unroll
                for (int k = 0; k < 4; ++k) {
                    float keep = b4 ? d[k + 4] : d[k];
                    float send = b4 ? d[k] : d[k + 4];
                    e[k] = keep + __shfl_xor(send, 4);
                }
                float f2_[2];
                #pragma unroll
                for (int k = 0; k < 2; ++k) {
                    float keep = b2 ? e[k + 2] : e[k];
                    float send = b2 ? e[k] : e[k + 2];
                    f2_[k] = keep + __shfl_xor(send, 2);
                }
                float keep = b1 ? f2_[1] : f2_[0];
                float send = b1 ? f2_[0] : f2_[1];
                rpx[px] = keep + __shfl_xor(send, 1);
            }
            float2* dst = reinterpret_cast<float2*>(lgp + ci_w * LGS) + co;
            float2 old = *dst;
            old.x += rpx[0]; old.y += rpx[1];
            *dst = old;
        }
        __syncthreads();                 // barrier 4 (dist1 -> softmax2)
    }

    // ---- output: grp 0 writes the wave's 64 cols, both pixels as float2
    if (grp == 0) {
        #pragma unroll
        for (int j = 0; j < 4; ++j) {
            int col = wv * 64 + j * 16 + lc;
            float2 v; v.x = act_[0][j]; v.y = act_[1][j];
            *reinterpret_cast<float2*>(out + ((((size_t)b << 8) + col) << 10) + hw0) = v;
        }
    }
}

extern "C" void kernel_launch(void* const* d_in, const int* in_sizes, int n_in,
                              void* d_out, int out_size, void* d_ws, size_t ws_size,
                              hipStream_t stream) {
    const float* x    = (const float*)d_in[0];
    const float* cw   = (const float*)d_in[1];
    const float* bias = (const float*)d_in[2];
    float* out = (float*)d_out;
    ushort* wp = (ushort*)d_ws;           // 256*96*2 = 49,152 B
    (void)in_sizes; (void)n_in; (void)out_size; (void)ws_size;
    prep_w<<<96, 256, 0, stream>>>(cw, wp);
    caps_mfma2<<<4096, 256, 0, stream>>>(x, wp, bias, out);
}

// Round 13
// 77.112 us; speedup vs baseline: 1.9154x; 1.9154x over previous
//
#include <hip/hip_runtime.h>

// Fused capsule conv + dynamic routing: 2 pixels/block, MFMA, XCD-ownership.
// x:      [8, 32, 8, 32, 32] f32   (bs, ci, ni, hi, wi)
// conv_w: [256, 8, 3, 3]     f32   (co*no, ni, kh, kw)
// bias:   [32, 8, 1, 1]      f32
// out:    [8, 32, 8, 32, 32] f32   (bs, co, no, ho, wo)
//
// R10 (86.7us, proven) with ONE change class: precise div/sqrt expansions
// replaced by __builtin_amdgcn_{sqrtf,rcpf} (single v_sqrt_f32/v_rcp_f32,
// compiler-visible -- NOT inline asm: R11's asm helpers extended live
// ranges at the exact 128-reg cap (64 VGPR + 64 AGPR acc) and spilled the
// accumulators -> 417 MB scratch traffic, 147us. Builtins are schedulable
// and rematerializable; they REDUCE pressure (no Newton temporaries).
// Kept from R10: pixel-pair ILP-2, single-term bf16 GEMM (K=96, 3 k-steps),
// 5 barriers, no-max-sub softmax, XCD-ownership swizzle, butterfly dist
// reduce, float2 stores, LB(256,4).

typedef __attribute__((ext_vector_type(8))) short short8;
typedef __attribute__((ext_vector_type(4))) float f32x4;

#define LSTR 104   // A row stride in ushorts (208 B)
#define KP   96    // packed K per col: [hi 72][zero 24]
#define RSTR 36    // routeT row stride (f32)

__device__ __forceinline__ ushort f2bf_rne(float f) {
    unsigned u = __float_as_uint(f);
    return (ushort)((u + 0x7fffu + ((u >> 16) & 1u)) >> 16);
}

__global__ void prep_w(const float* __restrict__ cw, ushort* __restrict__ wp) {
    int e = blockIdx.x * 256 + threadIdx.x;   // [col=256][k=96]
    int col = e / KP, k = e - col * KP;
    float v = (k < 72) ? cw[col * 72 + k] : 0.0f;
    wp[e] = f2bf_rne(v);
}

__global__ __launch_bounds__(256, 4)
void caps_mfma2(const float* __restrict__ x,
                const ushort* __restrict__ wp,
                const float* __restrict__ bias,
                float* __restrict__ out)
{
    __shared__ ushort A[64 * LSTR];        // 13,312 B
    __shared__ float  logits[2][32 * 33];  //  8,448 B  [px][ci][co]
    __shared__ float  routeT[2][32 * RSTR];//  9,216 B  [px][co][ci]

    const int t    = threadIdx.x;
    const int braw = blockIdx.x;                 // grid = 4096
    // XCD-ownership swizzle (bijective, 4096 = 8*512): XCD k owns batch k.
    const int bid = ((braw & 7) << 9) | (braw >> 3);
    const int b   = bid >> 9;
    const int q   = bid & 511;
    const int hw0 = q << 1;                      // even; pair = (hw0, hw0+1)
    const int h   = hw0 >> 5;
    const int w0  = hw0 & 31;                    // even, <= 30

    // ---- stage A rows: thread t <-> (row = t>>2 = px*32+ci, ni in {2qn,2qn+1})
    {
        const int row = t >> 2, qn = t & 3;
        const int px = row >> 5, ci = row & 31;
        const int wpx = w0 + px;
        const float* xb0 = x + (((size_t)((b * 32 + ci) * 8 + qn * 2)) << 10);
        const float* xb1 = xb0 + 1024;
        ushort hbuf[18];
        #pragma unroll
        for (int kh = 0; kh < 3; ++kh) {
            int hy = h + kh - 1;
            bool vh = (unsigned)hy < 32u;
            int base = hy << 5;
            #pragma unroll
            for (int c = 0; c < 3; ++c) {
                int wx = wpx + c - 1;
                bool ok = vh && ((unsigned)wx < 32u);
                float f0 = ok ? xb0[base + wx] : 0.0f;
                float f1 = ok ? xb1[base + wx] : 0.0f;
                hbuf[kh * 3 + c]     = f2bf_rne(f0);
                hbuf[9 + kh * 3 + c] = f2bf_rne(f1);
            }
        }
        // packed uint writes: shorts [row*LSTR + qn*18, +18)
        uint* Au = reinterpret_cast<uint*>(A);
        int hbase = row * (LSTR / 2) + qn * 9;
        #pragma unroll
        for (int i = 0; i < 9; ++i)
            Au[hbase + i] = (unsigned)hbuf[2 * i] | ((unsigned)hbuf[2 * i + 1] << 16);
        // zero K-pad shorts 72..103 (16 uints/row, 4 threads -> 4 each)
        int pbase = row * (LSTR / 2) + 36 + qn * 4;
        Au[pbase + 0] = 0u; Au[pbase + 1] = 0u;
        Au[pbase + 2] = 0u; Au[pbase + 3] = 0u;
    }
    __syncthreads();                     // barrier 1 (staging -> GEMM)

    const int lane = t & 63, wv = t >> 6;
    const int lc = lane & 15, grp = lane >> 4;
    const int no = lane & 7;
    const int par = (lane >> 3) & 1;

    // ---- GEMM: D[64 rows][256 cols], rows = px*32+ci. 3 k-steps of 32.
    f32x4 acc[4][4];
    #pragma unroll
    for (int mt = 0; mt < 4; ++mt)
        #pragma unroll
        for (int j = 0; j < 4; ++j) acc[mt][j] = (f32x4){0.f, 0.f, 0.f, 0.f};

    #pragma unroll
    for (int ks = 0; ks < 3; ++ks) {
        short8 bq[4];
        #pragma unroll
        for (int j = 0; j < 4; ++j) {
            int col = wv * 64 + j * 16 + lc;
            bq[j] = *reinterpret_cast<const short8*>(wp + col * KP + ks * 32 + grp * 8);
        }
        #pragma unroll
        for (int mt = 0; mt < 4; ++mt) {
            short8 af = *reinterpret_cast<const short8*>(A + (mt * 16 + lc) * LSTR + ks * 32 + grp * 8);
            #pragma unroll
            for (int j = 0; j < 4; ++j)
                acc[mt][j] = __builtin_amdgcn_mfma_f32_16x16x32_bf16(af, bq[j], acc[mt][j], 0, 0, 0);
        }
    }
    // no barrier: A is read-only from here; routing uses separate buffers

    float bj[4];
    #pragma unroll
    for (int j = 0; j < 4; ++j) bj[j] = bias[wv * 64 + j * 16 + lc];

    const int ci_s = t >> 3, j_s = t & 7;
    float act_[2][4];

    // ================= iteration 0: route = 1/32 exactly =================
    #pragma unroll
    for (int px = 0; px < 2; ++px) {
        #pragma unroll
        for (int j = 0; j < 4; ++j) {
            const f32x4 a0 = acc[px * 2][j], a1 = acc[px * 2 + 1][j];
            float p = a0[0] + a0[1] + a0[2] + a0[3] + a1[0] + a1[1] + a1[2] + a1[3];
            p += __shfl_xor(p, 16);
            p += __shfl_xor(p, 32);             // sum over 32 ci
            p = p * 0.03125f + bj[j];
            float s2 = p * p;
            s2 += __shfl_xor(s2, 1);
            s2 += __shfl_xor(s2, 2);
            s2 += __shfl_xor(s2, 4);            // sum over no
            act_[px][j] = p * __builtin_amdgcn_sqrtf(s2)
                            * __builtin_amdgcn_rcpf(1.0f + s2);
        }
    }
    // distances -> logits (pure write of all 1024 (ci,co) per pixel)
    #pragma unroll
    for (int px = 0; px < 2; ++px) {
        float* lg = logits[px];
        #pragma unroll
        for (int j = 0; j < 4; ++j) {
            float a = act_[px][j];
            float d[8];
            #pragma unroll
            for (int r = 0; r < 4; ++r) { d[r] = acc[px * 2][j][r] * a; d[4 + r] = acc[px * 2 + 1][j][r] * a; }
            const bool b4 = (no & 4) != 0, b2 = (no & 2) != 0, b1 = (no & 1) != 0;
            float e[4];
            #pragma unroll
            for (int k = 0; k < 4; ++k) {
                float keep = b4 ? d[k + 4] : d[k];
                float send = b4 ? d[k] : d[k + 4];
                e[k] = keep + __shfl_xor(send, 4);
            }
            float f2_[2];
            #pragma unroll
            for (int k = 0; k < 2; ++k) {
                float keep = b2 ? e[k + 2] : e[k];
                float send = b2 ? e[k] : e[k + 2];
                f2_[k] = keep + __shfl_xor(send, 2);
            }
            float keep = b1 ? f2_[1] : f2_[0];
            float send = b1 ? f2_[0] : f2_[1];
            float r = keep + __shfl_xor(send, 1);
            int ci_w = ((no >> 2) << 4) + (grp << 2) + (no & 3);
            int co   = (wv << 3) + 2 * j + par;
            lg[ci_w * 33 + co] = r;
        }
    }
    __syncthreads();                     // barrier 2 (dist0 -> softmax1)

    // ================= iterations 1 and 2 =================
    for (int it = 1; it <= 2; ++it) {
        // (a) softmax over co per pixel (no max-subtract: |logits| small);
        //     store transposed routeT[co][ci]
        #pragma unroll
        for (int px = 0; px < 2; ++px) {
            const float* lg = logits[px];
            float* rt = routeT[px];
            float e0 = __expf(lg[ci_s * 33 + j_s]);
            float e1 = __expf(lg[ci_s * 33 + j_s + 8]);
            float e2 = __expf(lg[ci_s * 33 + j_s + 16]);
            float e3 = __expf(lg[ci_s * 33 + j_s + 24]);
            float s = e0 + e1 + e2 + e3;
            s += __shfl_xor(s, 1); s += __shfl_xor(s, 2); s += __shfl_xor(s, 4);
            float inv = __builtin_amdgcn_rcpf(s);
            rt[(j_s)      * RSTR + ci_s] = e0 * inv;
            rt[(j_s + 8)  * RSTR + ci_s] = e1 * inv;
            rt[(j_s + 16) * RSTR + ci_s] = e2 * inv;
            rt[(j_s + 24) * RSTR + ci_s] = e3 * inv;
        }
        __syncthreads();                 // barrier 3 / 5 (routeT -> preact)

        // (b) preactivate (ci-reduce xor16/32) + squash (no-reduce xor1/2/4)
        #pragma unroll
        for (int px = 0; px < 2; ++px) {
            const float* rt = routeT[px];
            #pragma unroll
            for (int j = 0; j < 4; ++j) {
                int co = (wv << 3) + 2 * j + par;
                f32x4 r0 = *reinterpret_cast<const f32x4*>(rt + co * RSTR + grp * 4);
                f32x4 r1 = *reinterpret_cast<const f32x4*>(rt + co * RSTR + 16 + grp * 4);
                float p = 0.0f;
                #pragma unroll
                for (int r = 0; r < 4; ++r) p = fmaf(r0[r], acc[px * 2][j][r], p);
                #pragma unroll
                for (int r = 0; r < 4; ++r) p = fmaf(r1[r], acc[px * 2 + 1][j][r], p);
                p += __shfl_xor(p, 16);
                p += __shfl_xor(p, 32);
                p += bj[j];
                float s2 = p * p;
                s2 += __shfl_xor(s2, 1);
                s2 += __shfl_xor(s2, 2);
                s2 += __shfl_xor(s2, 4);
                act_[px][j] = p * __builtin_amdgcn_sqrtf(s2)
                                * __builtin_amdgcn_rcpf(1.0f + s2);
            }
        }
        if (it == 2) break;

        // (c) distances += (butterfly), accumulate into logits
        #pragma unroll
        for (int px = 0; px < 2; ++px) {
            float* lg = logits[px];
            #pragma unroll
            for (int j = 0; j < 4; ++j) {
                float a = act_[px][j];
                float d[8];
                #pragma unroll
                for (int r = 0; r < 4; ++r) { d[r] = acc[px * 2][j][r] * a; d[4 + r] = acc[px * 2 + 1][j][r] * a; }
                const bool b4 = (no & 4) != 0, b2 = (no & 2) != 0, b1 = (no & 1) != 0;
                float e[4];
                #pragma unroll
                for (int k = 0; k < 4; ++k) {
                    float keep = b4 ? d[k + 4] : d[k];
                    float send = b4 ? d[k] : d[k + 4];
                    e[k] = keep + __shfl_xor(send, 4);
                }
                float f2_[2];
                #pragma unroll
                for (int k = 0; k < 2; ++k) {
                    float keep = b2 ? e[k + 2] : e[k];
                    float send = b2 ? e[k] : e[k + 2];
                    f2_[k] = keep + __shfl_xor(send, 2);
                }
                float keep = b1 ? f2_[1] : f2_[0];
                float send = b1 ? f2_[0] : f2_[1];
                float r = keep + __shfl_xor(send, 1);
                int ci_w = ((no >> 2) << 4) + (grp << 2) + (no & 3);
                int co   = (wv << 3) + 2 * j + par;
                lg[ci_w * 33 + co] += r;
            }
        }
        __syncthreads();                 // barrier 4 (dist1 -> softmax2)
    }

    // ---- output: grp 0 writes the wave's 64 cols, both pixels as float2
    if (grp == 0) {
        #pragma unroll
        for (int j = 0; j < 4; ++j) {
            int col = wv * 64 + j * 16 + lc;
            float2 v; v.x = act_[0][j]; v.y = act_[1][j];
            *reinterpret_cast<float2*>(out + ((((size_t)b << 8) + col) << 10) + hw0) = v;
        }
    }
}

extern "C" void kernel_launch(void* const* d_in, const int* in_sizes, int n_in,
                              void* d_out, int out_size, void* d_ws, size_t ws_size,
                              hipStream_t stream) {
    const float* x    = (const float*)d_in[0];
    const float* cw   = (const float*)d_in[1];
    const float* bias = (const float*)d_in[2];
    float* out = (float*)d_out;
    ushort* wp = (ushort*)d_ws;           // 256*96*2 = 49,152 B
    (void)in_sizes; (void)n_in; (void)out_size; (void)ws_size;
    prep_w<<<96, 256, 0, stream>>>(cw, wp);
    caps_mfma2<<<4096, 256, 0, stream>>>(x, wp, bias, out);
}